// Round 1
// baseline (205.951 us; speedup 1.0000x reference)
//
#include <hip/hip_runtime.h>
#include <math.h>

// Separator: residual_model + softmask, float32 throughout.
// v: (1, 2560, 2049, 2, 4)  x: (1, 2560, 2049, 2, 2)  out: (1, 2560, 2049, 2, 2, 5)

#define EPS 1.1920928955078125e-07f   // FLT_EPSILON, matches jnp.finfo(float32).eps

static constexpr int T_FRAMES = 2560;
static constexpr int FC       = 2049 * 2;          // 4098 (f,c) columns
static constexpr int NCHUNK   = 80;                // t-chunks for reduction parallelism
static constexpr int TPC      = T_FRAMES / NCHUNK; // 32 frames per chunk

// Pass 1: per-column partial sums over a chunk of frames, accumulated with atomics.
// gw[col*2+0] = sum_t vx * v_total ; gw[col*2+1] = sum_t v_total^2
__global__ __launch_bounds__(256) void sep_reduce(
    const float* __restrict__ v, const float* __restrict__ x,
    float* __restrict__ gw) {
    const int col = blockIdx.x * 256 + threadIdx.x;
    if (col >= FC) return;
    const int t0 = blockIdx.y * TPC;
    const float4* vp = reinterpret_cast<const float4*>(v) + (size_t)t0 * FC + col;
    const float2* xp = reinterpret_cast<const float2*>(x) + (size_t)t0 * FC + col;
    float pg = 0.f, pw = 0.f;
    #pragma unroll 4
    for (int t = 0; t < TPC; ++t) {
        float4 vv = vp[(size_t)t * FC];
        float2 xx = xp[(size_t)t * FC];
        float vt  = (vv.x + vv.y) + (vv.z + vv.w);
        float mag = sqrtf(xx.x * xx.x + xx.y * xx.y);
        float vx  = fmaxf(EPS, mag);
        pg = fmaf(vx, vt, pg);
        pw = fmaf(vt, vt, pw);
    }
    atomicAdd(&gw[col * 2 + 0], pg);
    atomicAdd(&gw[col * 2 + 1], pw);
}

// Pass 2: elementwise apply. One thread per (t, f, c) element.
__global__ __launch_bounds__(256) void sep_apply(
    const float* __restrict__ v, const float* __restrict__ x,
    const float* __restrict__ gw, float* __restrict__ out) {
    const int col = blockIdx.x * 256 + threadIdx.x;
    if (col >= FC) return;
    const int t = blockIdx.y;
    const size_t i = (size_t)t * FC + col;

    float4 vv = reinterpret_cast<const float4*>(v)[i];
    float2 xx = reinterpret_cast<const float2*>(x)[i];
    float g = gw[col * 2 + 0];
    float w = gw[col * 2 + 1];
    float s = g / (EPS + w);                 // gain / weights

    float v0 = vv.x * s, v1 = vv.y * s, v2 = vv.z * s, v3 = vv.w * s;
    float vt  = (v0 + v1) + (v2 + v3);
    float mag = sqrtf(xx.x * xx.x + xx.y * xx.y);
    float vx  = fmaxf(EPS, mag);
    float vr  = fmaxf(0.f, vx - vt);         // relu(vx - v_total)
    float inv = 1.f / (EPS + vt + vr);       // softmask denom
    float m0 = v0 * inv, m1 = v1 * inv, m2 = v2 * inv, m3 = v3 * inv, mr = vr * inv;

    // out layout: [t][f][c][ri][j], 10 floats per (t,f,c); base is 8B-aligned -> float2 stores
    float2* o = reinterpret_cast<float2*>(out + i * 10);
    o[0] = make_float2(xx.x * m0, xx.x * m1);
    o[1] = make_float2(xx.x * m2, xx.x * m3);
    o[2] = make_float2(xx.x * mr, xx.y * m0);
    o[3] = make_float2(xx.y * m1, xx.y * m2);
    o[4] = make_float2(xx.y * m3, xx.y * mr);
}

extern "C" void kernel_launch(void* const* d_in, const int* in_sizes, int n_in,
                              void* d_out, int out_size, void* d_ws, size_t ws_size,
                              hipStream_t stream) {
    const float* v = (const float*)d_in[0];
    const float* x = (const float*)d_in[1];
    float* out = (float*)d_out;
    float* gw  = (float*)d_ws;   // FC*2 floats = 32 KB

    hipMemsetAsync(gw, 0, (size_t)FC * 2 * sizeof(float), stream);

    dim3 rgrid((FC + 255) / 256, NCHUNK);
    sep_reduce<<<rgrid, 256, 0, stream>>>(v, x, gw);

    dim3 agrid((FC + 255) / 256, T_FRAMES);
    sep_apply<<<agrid, 256, 0, stream>>>(v, x, gw, out);
}

// Round 2
// 177.967 us; speedup vs baseline: 1.1572x; 1.1572x over previous
//
#include <hip/hip_runtime.h>
#include <math.h>

// Separator: residual_model + softmask, float32 throughout.
// v: (1, 2560, 2049, 2, 4)  x: (1, 2560, 2049, 2, 2)  out: (1, 2560, 2049, 2, 2, 5)

#define EPS 1.1920928955078125e-07f   // FLT_EPSILON, matches jnp.finfo(float32).eps

static constexpr int T_FRAMES = 2560;
static constexpr int FC       = 2049 * 2;            // 4098 (f,c) columns
static constexpr unsigned TFC = (unsigned)T_FRAMES * FC;  // 10,490,880 (divisible by 256)
static constexpr int NCHUNK   = 80;                  // t-chunks for reduction parallelism
static constexpr int TPC      = T_FRAMES / NCHUNK;   // 32 frames per chunk

// Pass 1: per-column partial sums over a chunk of frames, accumulated with atomics.
// gw[col*2+0] = sum_t vx * v_total ; gw[col*2+1] = sum_t v_total^2
// Chunks are processed in REVERSE t order so that the L3 retains the low-t
// frames when pass 2 (which reads t ascending) starts.
__global__ __launch_bounds__(256) void sep_reduce(
    const float* __restrict__ v, const float* __restrict__ x,
    float* __restrict__ gw) {
    const int col = blockIdx.x * 256 + threadIdx.x;
    if (col >= FC) return;
    const int t0 = (NCHUNK - 1 - blockIdx.y) * TPC;
    const float4* vp = reinterpret_cast<const float4*>(v) + (size_t)t0 * FC + col;
    const float2* xp = reinterpret_cast<const float2*>(x) + (size_t)t0 * FC + col;
    float pg = 0.f, pw = 0.f;
    #pragma unroll 4
    for (int t = 0; t < TPC; ++t) {
        float4 vv = vp[(size_t)t * FC];
        float2 xx = xp[(size_t)t * FC];
        float vt  = (vv.x + vv.y) + (vv.z + vv.w);
        float mag = sqrtf(xx.x * xx.x + xx.y * xx.y);
        float vx  = fmaxf(EPS, mag);
        pg = fmaf(vx, vt, pg);
        pw = fmaf(vt, vt, pw);
    }
    atomicAdd(&gw[col * 2 + 0], pg);
    atomicAdd(&gw[col * 2 + 1], pw);
}

// Pass 2: elementwise apply over flat (t,f,c) index. Outputs staged in LDS so
// global stores are fully coalesced (block's output region = 2560 contiguous
// floats; every block is full since TFC % 256 == 0).
__global__ __launch_bounds__(256) void sep_apply(
    const float* __restrict__ v, const float* __restrict__ x,
    const float* __restrict__ gw, float* __restrict__ out) {
    __shared__ float lds[256 * 10];
    const unsigned tid = threadIdx.x;
    const unsigned i   = blockIdx.x * 256u + tid;   // flat (t,f,c), < TFC
    const unsigned col = i % (unsigned)FC;

    float4 vv = reinterpret_cast<const float4*>(v)[i];
    float2 xx = reinterpret_cast<const float2*>(x)[i];
    float g = gw[col * 2 + 0];
    float w = gw[col * 2 + 1];
    float s = g / (EPS + w);                 // gain / weights

    float v0 = vv.x * s, v1 = vv.y * s, v2 = vv.z * s, v3 = vv.w * s;
    float vt  = (v0 + v1) + (v2 + v3);
    float mag = sqrtf(xx.x * xx.x + xx.y * xx.y);
    float vx  = fmaxf(EPS, mag);
    float vr  = fmaxf(0.f, vx - vt);                 // relu(vx - v_total)
    float inv = 1.f / (EPS + fmaxf(vt, vx));         // eps + vt + vr == eps + max(vt,vx)
    float m0 = v0 * inv, m1 = v1 * inv, m2 = v2 * inv, m3 = v3 * inv, mr = vr * inv;

    // out element layout per (t,f,c): [ri=0..1][j=0..4]
    float2* l2 = reinterpret_cast<float2*>(lds) + tid * 5;
    l2[0] = make_float2(xx.x * m0, xx.x * m1);
    l2[1] = make_float2(xx.x * m2, xx.x * m3);
    l2[2] = make_float2(xx.x * mr, xx.y * m0);
    l2[3] = make_float2(xx.y * m1, xx.y * m2);
    l2[4] = make_float2(xx.y * m3, xx.y * mr);

    __syncthreads();

    const float2* ls = reinterpret_cast<const float2*>(lds);
    float2* o2 = reinterpret_cast<float2*>(out) + (size_t)blockIdx.x * 1280;
    #pragma unroll
    for (int k = 0; k < 5; ++k)
        o2[k * 256 + tid] = ls[k * 256 + tid];
}

extern "C" void kernel_launch(void* const* d_in, const int* in_sizes, int n_in,
                              void* d_out, int out_size, void* d_ws, size_t ws_size,
                              hipStream_t stream) {
    const float* v = (const float*)d_in[0];
    const float* x = (const float*)d_in[1];
    float* out = (float*)d_out;
    float* gw  = (float*)d_ws;   // FC*2 floats = 32 KB

    hipMemsetAsync(gw, 0, (size_t)FC * 2 * sizeof(float), stream);

    dim3 rgrid((FC + 255) / 256, NCHUNK);
    sep_reduce<<<rgrid, 256, 0, stream>>>(v, x, gw);

    sep_apply<<<dim3(TFC / 256), 256, 0, stream>>>(v, x, gw, out);
}

// Round 4
// 143.718 us; speedup vs baseline: 1.4330x; 1.2383x over previous
//
#include <hip/hip_runtime.h>
#include <math.h>

// Separator: residual_model + softmask, float32 throughout.
// v: (1, 2560, 2049, 2, 4)  x: (1, 2560, 2049, 2, 2)  out: (1, 2560, 2049, 2, 2, 5)

#define EPS 1.1920928955078125e-07f   // FLT_EPSILON, matches jnp.finfo(float32).eps

typedef float f32x2 __attribute__((ext_vector_type(2)));  // clang vector: valid for nontemporal builtins

static constexpr int T_FRAMES = 2560;
static constexpr int FC       = 2049 * 2;            // 4098 (f,c) columns
static constexpr unsigned TFC = (unsigned)T_FRAMES * FC;  // 10,490,880 (divisible by 256)
static constexpr int NCHUNK   = 80;                  // t-chunks for reduction parallelism
static constexpr int TPC      = T_FRAMES / NCHUNK;   // 32 frames per chunk

// Pass 1: per-column partial sums over a chunk of frames, accumulated with atomics.
// gw[col*2+0] = sum_t vx * v_total ; gw[col*2+1] = sum_t v_total^2
// Chunks run in REVERSE t order so the L3 holds low-t frames when pass 2
// (ascending t) starts. Loads allocate normally — we WANT v,x resident in L3.
__global__ __launch_bounds__(256) void sep_reduce(
    const float* __restrict__ v, const float* __restrict__ x,
    float* __restrict__ gw) {
    const int col = blockIdx.x * 256 + threadIdx.x;
    if (col >= FC) return;
    const int t0 = (NCHUNK - 1 - blockIdx.y) * TPC;
    const float4* vp = reinterpret_cast<const float4*>(v) + (size_t)t0 * FC + col;
    const float2* xp = reinterpret_cast<const float2*>(x) + (size_t)t0 * FC + col;
    float pg = 0.f, pw = 0.f;
    #pragma unroll 4
    for (int t = 0; t < TPC; ++t) {
        float4 vv = vp[(size_t)t * FC];
        float2 xx = xp[(size_t)t * FC];
        float vt  = (vv.x + vv.y) + (vv.z + vv.w);
        float mag = sqrtf(xx.x * xx.x + xx.y * xx.y);
        float vx  = fmaxf(EPS, mag);
        pg = fmaf(vx, vt, pg);
        pw = fmaf(vt, vt, pw);
    }
    atomicAdd(&gw[col * 2 + 0], pg);
    atomicAdd(&gw[col * 2 + 1], pw);
}

// Pass 2: elementwise apply over flat (t,f,c). Outputs staged in LDS for fully
// coalesced stores, then written NON-TEMPORALLY so the 420 MB write-once
// stream does not evict the L3-resident v/x lines this pass re-reads.
__global__ __launch_bounds__(256) void sep_apply(
    const float* __restrict__ v, const float* __restrict__ x,
    const float* __restrict__ gw, float* __restrict__ out) {
    __shared__ float lds[256 * 10];
    const unsigned tid = threadIdx.x;
    const unsigned i   = blockIdx.x * 256u + tid;   // flat (t,f,c), < TFC
    const unsigned col = i % (unsigned)FC;

    float4 vv = reinterpret_cast<const float4*>(v)[i];
    float2 xx = reinterpret_cast<const float2*>(x)[i];
    float g = gw[col * 2 + 0];
    float w = gw[col * 2 + 1];
    float s = g / (EPS + w);                 // gain / weights

    float v0 = vv.x * s, v1 = vv.y * s, v2 = vv.z * s, v3 = vv.w * s;
    float vt  = (v0 + v1) + (v2 + v3);
    float mag = sqrtf(xx.x * xx.x + xx.y * xx.y);
    float vx  = fmaxf(EPS, mag);
    float vr  = fmaxf(0.f, vx - vt);                 // relu(vx - v_total)
    float inv = 1.f / (EPS + fmaxf(vt, vx));         // eps + vt + vr == eps + max(vt,vx)
    float m0 = v0 * inv, m1 = v1 * inv, m2 = v2 * inv, m3 = v3 * inv, mr = vr * inv;

    // out element layout per (t,f,c): [ri=0..1][j=0..4]
    float2* l2 = reinterpret_cast<float2*>(lds) + tid * 5;
    l2[0] = make_float2(xx.x * m0, xx.x * m1);
    l2[1] = make_float2(xx.x * m2, xx.x * m3);
    l2[2] = make_float2(xx.x * mr, xx.y * m0);
    l2[3] = make_float2(xx.y * m1, xx.y * m2);
    l2[4] = make_float2(xx.y * m3, xx.y * mr);

    __syncthreads();

    const f32x2* ls = reinterpret_cast<const f32x2*>(lds);
    f32x2* o2 = reinterpret_cast<f32x2*>(out) + (size_t)blockIdx.x * 1280;
    #pragma unroll
    for (int k = 0; k < 5; ++k)
        __builtin_nontemporal_store(ls[k * 256 + tid], &o2[k * 256 + tid]);
}

extern "C" void kernel_launch(void* const* d_in, const int* in_sizes, int n_in,
                              void* d_out, int out_size, void* d_ws, size_t ws_size,
                              hipStream_t stream) {
    const float* v = (const float*)d_in[0];
    const float* x = (const float*)d_in[1];
    float* out = (float*)d_out;
    float* gw  = (float*)d_ws;   // FC*2 floats = 32 KB

    (void)hipMemsetAsync(gw, 0, (size_t)FC * 2 * sizeof(float), stream);

    dim3 rgrid((FC + 255) / 256, NCHUNK);
    sep_reduce<<<rgrid, 256, 0, stream>>>(v, x, gw);

    sep_apply<<<dim3(TFC / 256), 256, 0, stream>>>(v, x, gw, out);
}